// Round 5
// baseline (544.169 us; speedup 1.0000x reference)
//
#include <hip/hip_runtime.h>
#include <stdint.h>
#include <stddef.h>

#define B_ROWS 16384
#define DIN 1024
#define DOUT 1024
#define KDIM 2048   // DIN + DOUT

#define BM 128
#define BNP 128     // packed N per block = 4 gates x 32 cols
#define BK 64

typedef __bf16 bf16x8 __attribute__((ext_vector_type(8)));
typedef float floatx16 __attribute__((ext_vector_type(16)));

__device__ __forceinline__ unsigned short f2bf(float f) {
  unsigned int u = __float_as_uint(f);
  u += 0x7fffu + ((u >> 16) & 1u);   // round-to-nearest-even
  return (unsigned short)(u >> 16);
}

__device__ __forceinline__ void async16(const void* g, void* l) {
  __builtin_amdgcn_global_load_lds(
      (__attribute__((address_space(1))) void*)(g),
      (__attribute__((address_space(3))) void*)(l), 16, 0, 0);
}

__device__ __forceinline__ float sigmoid_f(float x) {
  return 1.0f / (1.0f + __expf(-x));
}
__device__ __forceinline__ float tanh_f(float x) {
  return 2.0f / (1.0f + __expf(-2.0f * x)) - 1.0f;
}

// ---------------- prep (single launch): cast X + transpose/pack W ----------
// blocks [0, 32768): cast & concat X = [inputs | hist] -> bf16 16384 x 2048
// blocks [32768, 40960): transpose W into gate-packed n-major layout:
//   packed row np = (n>>5)*128 + g*32 + (n&31), row length KDIM (k-major).
//   One GEMM block (128 packed rows) = all 4 gates for the same 32 cols;
//   each 32-row n-tile is ONE gate -> 32x32 MFMA n-tile == gate.
//   z = 2*g + part; part0 = Wx (k 0..1023), part1 = Wh (k 1024..2047)
__global__ void prep_kernel(
    const float* __restrict__ inp, const float* __restrict__ hist,
    const float* __restrict__ s0, const float* __restrict__ s1,
    const float* __restrict__ s2, const float* __restrict__ s3,
    const float* __restrict__ s4, const float* __restrict__ s5,
    const float* __restrict__ s6, const float* __restrict__ s7,
    unsigned short* __restrict__ xb, unsigned short* __restrict__ wt) {
  __shared__ float tile[32][33];
  const int tid = threadIdx.x;
  if (blockIdx.x < 32768) {
    int idx = blockIdx.x * 256 + tid;           // one float4 per thread
    const int per = B_ROWS * DIN / 4;
    const float* src;
    int colOff;
    int i = idx;
    if (i < per) { src = inp; colOff = 0; }
    else         { src = hist; colOff = DIN; i -= per; }
    int e = i * 4;
    int row = e >> 10;
    int col = e & 1023;
    const float4 v = *(const float4*)(src + (size_t)row * 1024 + col);
    ushort4 o;
    o.x = f2bf(v.x); o.y = f2bf(v.y); o.z = f2bf(v.z); o.w = f2bf(v.w);
    *(ushort4*)(xb + (size_t)row * KDIM + colOff + col) = o;
    return;
  }
  const int bb = blockIdx.x - 32768;            // 0..8191 = 32 x 32 x 8
  const int bx = bb & 31, by = (bb >> 5) & 31, z = bb >> 10;
  const float* src;
  switch (z) {
    case 0: src = s0; break; case 1: src = s1; break;
    case 2: src = s2; break; case 3: src = s3; break;
    case 4: src = s4; break; case 5: src = s5; break;
    case 6: src = s6; break; default: src = s7; break;
  }
  const int g = z >> 1, part = z & 1;
  const int tx = tid & 31, ty = tid >> 5;       // 32 x 8
  const int n0 = bx * 32, k0 = by * 32;
#pragma unroll
  for (int j = 0; j < 32; j += 8)
    tile[ty + j][tx] = src[(size_t)(k0 + ty + j) * DOUT + n0 + tx];
  __syncthreads();
#pragma unroll
  for (int j = 0; j < 32; j += 8) {
    const int n = n0 + ty + j;
    const int np = ((n >> 5) << 7) + g * 32 + (n & 31);
    wt[(size_t)np * KDIM + part * DIN + k0 + tx] = f2bf(tile[tx][ty + j]);
  }
}

// ---- single-pass 4-gate GEMM + LSTM epilogue (32x32x16 MFMA) ----
// Block: 128 rows x 32 output cols x 4 gates (packed N=128), 4 waves on M.
// Wave tile 32 x 128 = 4 n-tiles of 32x32; n-tile ni == gate ni, so each
// lane holds f,i,o,c for the same (row,col) -> thread-local combine.
// Per K-tile: 4 k-steps of K=16, each 1 a-frag + 4 b-frags + 4 MFMA
// (16 MFMA/K-tile vs 32 for 16x16x32; per-SIMD pipe cycles -17%).
// Fragment maps: A row=lane&31, k=(lane>>5)*8+j (contiguous 8 along K);
// B col=lane&31, same k -> identical LDS read pattern for A and B.
// C/D: col=lane&31, row=(reg&3)+8*(reg>>2)+4*(lane>>5)  [m74/m101].
// LDS XOR-swizzle: slot (row,t) holds global chunk t^(row&7); read side
// XORs with lane&7 (== row&7 for both A and B rows here).
__global__ __launch_bounds__(256, 4) void lstm_fused_kernel(
    const unsigned short* __restrict__ Xb,    // 16384 x 2048 bf16
    const unsigned short* __restrict__ Wt2,   // 4096 x 2048 bf16 packed
    const float* __restrict__ b_f, const float* __restrict__ b_i,
    const float* __restrict__ b_o, const float* __restrict__ b_c,
    const int* __restrict__ carousel,
    float* __restrict__ out) {                // h (16384x1024) then c
  __shared__ unsigned short As[BM * BK];
  __shared__ unsigned short Bs[BNP * BK];

  const int tid  = threadIdx.x;
  const int lane = tid & 63;
  const int wave = tid >> 6;
  const int wm   = wave * 32;
  const int l31  = lane & 31;
  const int kg   = lane >> 5;               // k-group (0/1)
  const int r7   = lane & 7;
  const int bm   = blockIdx.y * BM;
  const int cg   = blockIdx.x;              // 32-col output group

  const unsigned short* Wp = Wt2 + (size_t)cg * BNP * KDIM;

  floatx16 acc[4];
#pragma unroll
  for (int ni = 0; ni < 4; ++ni)
#pragma unroll
    for (int r = 0; r < 16; ++r)
      acc[ni][r] = 0.f;

  // staging indices (swizzled global source chunk per LDS slot)
  int srow[4], scol[4];
#pragma unroll
  for (int j = 0; j < 4; ++j) {
    const int c = j * 256 + tid;
    srow[j] = c >> 3;
    scol[j] = (c & 7) ^ (srow[j] & 7);
  }

  const unsigned short* Arow = As + (wm + l31) * BK;
  const unsigned short* Brow = Bs + l31 * BK;

  for (int kt = 0; kt < KDIM; kt += BK) {
#pragma unroll
    for (int j = 0; j < 4; ++j) {
      const int c = j * 256 + tid;
      async16(Xb + (size_t)(bm + srow[j]) * KDIM + kt + scol[j] * 8, As + c * 8);
    }
#pragma unroll
    for (int j = 0; j < 4; ++j) {
      const int c = j * 256 + tid;
      async16(Wp + (size_t)srow[j] * KDIM + kt + scol[j] * 8, Bs + c * 8);
    }
    __syncthreads();
#pragma unroll
    for (int ks = 0; ks < 4; ++ks) {
      const int t = (ks * 2 + kg) ^ r7;     // chunk holding k = ks*16 + kg*8
      const bf16x8 av = *(const bf16x8*)(Arow + t * 8);
      bf16x8 bv[4];
#pragma unroll
      for (int ni = 0; ni < 4; ++ni)
        bv[ni] = *(const bf16x8*)(Brow + ni * 32 * BK + t * 8);
#pragma unroll
      for (int ni = 0; ni < 4; ++ni)
        acc[ni] = __builtin_amdgcn_mfma_f32_32x32x16_bf16(
            av, bv[ni], acc[ni], 0, 0, 0);
    }
    __syncthreads();
  }

  // epilogue: combine gates, write h and c (thread-local, ni == gate)
  const float cf = (float)carousel[0];
  const int col  = cg * 32 + l31;
  const float bfv = b_f[col], biv = b_i[col], bov = b_o[col], bcv = b_c[col];
  const int rb = bm + wm + 4 * kg;

#pragma unroll
  for (int r = 0; r < 16; ++r) {
    const int row = rb + (r & 3) + 8 * (r >> 2);
    const float f = sigmoid_f(acc[0][r] + bfv);
    const float i = sigmoid_f(acc[1][r] + biv);
    const float o = sigmoid_f(acc[2][r] + bov);
    const float g = tanh_f   (acc[3][r] + bcv);
    const float c = f * cf + i * g;
    const float h = o * c;
    out[(size_t)row * DOUT + col] = h;
    out[(size_t)(B_ROWS * DOUT) + (size_t)row * DOUT + col] = c;
  }
}

extern "C" void kernel_launch(void* const* d_in, const int* in_sizes, int n_in,
                              void* d_out, int out_size, void* d_ws, size_t ws_size,
                              hipStream_t stream) {
  const float* inputs = (const float*)d_in[0];
  const float* hist   = (const float*)d_in[1];
  const int* carousel = (const int*)d_in[2];
  const float* Wfx = (const float*)d_in[3];
  const float* Wfh = (const float*)d_in[4];
  const float* bfv = (const float*)d_in[5];
  const float* Wix = (const float*)d_in[6];
  const float* Wih = (const float*)d_in[7];
  const float* biv = (const float*)d_in[8];
  const float* Wox = (const float*)d_in[9];
  const float* Woh = (const float*)d_in[10];
  const float* bov = (const float*)d_in[11];
  const float* Wcx = (const float*)d_in[12];
  const float* Wch = (const float*)d_in[13];
  const float* bcv = (const float*)d_in[14];

  unsigned short* Xb  = (unsigned short*)d_ws;               // 64 MB
  unsigned short* Wt2 = Xb + (size_t)B_ROWS * KDIM;          // 16 MB

  prep_kernel<<<40960, 256, 0, stream>>>(
      inputs, hist, Wfx, Wfh, Wix, Wih, Wox, Woh, Wcx, Wch, Xb, Wt2);

  dim3 grid(DOUT / 32, B_ROWS / BM);                         // 32 x 128
  lstm_fused_kernel<<<grid, 256, 0, stream>>>(
      Xb, Wt2, bfv, biv, bov, bcv, carousel, (float*)d_out);
}